// Round 4
// baseline (12268.076 us; speedup 1.0000x reference)
//
#include <hip/hip_runtime.h>
#include <cstdint>

#define NB 128      // batch
#define DH 512      // D == H
#define ROWS 528    // DH + 16 pad rows (legacy; loops no longer overrun)

// ---- workspace layout (float offsets) ----
#define OFF_M   0u          // [128 chunks][512 k][16 c]  folded [Ar|Az|Ah|Wo]
#define OFF_M1  1048576u    // [128][512][16]             step-1 [Wr|Wz|Wh|0]
#define OFF_UH  2097152u    // [128 chunks][512 k][4 c]   Uh
#define OFF_H   2359296u    // [528][128]  h (transposed, padded)
#define OFF_RH  2426880u    // [528][128]  r*h
#define OFF_XT  2494464u    // [528][128]  inputs^T
#define OFF_GZ  2562048u    // [512][128]  z gate (activated)
#define OFF_GH  2627584u    // [512][128]  pre-h (x-part + bias)
#define OFF_CV  2693120u    // [2048] folded biases
#define OFF_C1  2695168u    // [2048] step-1 biases
#define OFF_BAR 2697216u    // 4096 uint32 barrier state (group-local, 128B-strided)

__device__ __forceinline__ float sigm(float x) { return 1.f / (1.f + __expf(-x)); }
__device__ __forceinline__ float tanh_fast(float x) {
  float e = __expf(2.f * fminf(x, 40.f));
  return (e - 1.f) / (e + 1.f);
}

// Coherent (agent-scope) access: compiles to global_load/store sc0 sc1 —
// always served at the coherence point, no cache-wide fences needed.
__device__ __forceinline__ float cload(const float* p) {
  return __hip_atomic_load(p, __ATOMIC_RELAXED, __HIP_MEMORY_SCOPE_AGENT);
}
__device__ __forceinline__ void cstore(float* p, float v) {
  __hip_atomic_store(p, v, __ATOMIC_RELAXED, __HIP_MEMORY_SCOPE_AGENT);
}

// ======================= precompute kernel =======================
__global__ __launch_bounds__(256) void gru_pre(
    const float* __restrict__ inputs,
    const float* __restrict__ Wz, const float* __restrict__ Wr, const float* __restrict__ Wh,
    const float* __restrict__ Uz, const float* __restrict__ Ur, const float* __restrict__ Uh,
    const float* __restrict__ bz, const float* __restrict__ br, const float* __restrict__ bh,
    const float* __restrict__ Wo, const float* __restrict__ bo,
    float* __restrict__ ws)
{
  __shared__ float sh[8960];            // 35 KB scratch, reused per task
  const int bid = blockIdx.x, t = threadIdx.x;
  float* Mw  = ws + OFF_M;
  float* M1w = ws + OFF_M1;
  float* Uhw = ws + OFF_UH;
  float* hw  = ws + OFF_H;
  float* rhw = ws + OFF_RH;
  float* xT  = ws + OFF_XT;
  float* cv  = ws + OFF_CV;
  float* c1  = ws + OFF_C1;
  uint32_t* bar = (uint32_t*)(ws + OFF_BAR);

  if (bid < 256) {
    // ---- build M = [Wo@Wr+Ur | Wo@Wz+Uz | Wo@Wh | Wo] ----
    const int kh = bid >> 7, cch = bid & 127;
    const int reg = cch >> 5;
    const int k0 = kh * 256, c0 = cch * 16;
    if (reg == 3) {
      const int cc0 = c0 - 1536;
      for (int i = 0; i < 16; ++i) {
        int idx = t + i * 256;
        int kk = k0 + (idx >> 4), ci = idx & 15;
        Mw[(cch * 512 + kk) * 16 + ci] = Wo[kk * 512 + cc0 + ci];
      }
    } else {
      const float* Ws = (reg == 0) ? Wr : (reg == 1) ? Wz : Wh;
      const float* Us = (reg == 0) ? Ur : (reg == 1) ? Uz : nullptr;
      const int cc0 = c0 - reg * 512;
      const int kl = t;                 // 256 threads <-> 256 local k rows
      const int k = k0 + kl;
      float acc[16];
      #pragma unroll
      for (int c = 0; c < 16; ++c) acc[c] = 0.f;
      for (int jt = 0; jt < 16; ++jt) {          // 32-wide j tiles of Wo
        __syncthreads();
        for (int i = 0; i < 32; ++i) {
          int idx = t + i * 256;                 // 8192 = 256k x 32j
          int kk = idx >> 5, jj = idx & 31;
          sh[kk * 35 + jj] = Wo[(k0 + kk) * 512 + jt * 32 + jj];
        }
        __syncthreads();
        for (int j = 0; j < 32; ++j) {
          float wv = sh[kl * 35 + j];
          const float* wrow = Ws + (jt * 32 + j) * 512 + cc0;
          #pragma unroll
          for (int c = 0; c < 16; ++c) acc[c] = fmaf(wv, wrow[c], acc[c]);
        }
      }
      #pragma unroll
      for (int c = 0; c < 16; ++c) {
        float v = acc[c];
        if (Us) v += Us[k * 512 + cc0 + c];
        Mw[(cch * 512 + k) * 16 + c] = v;
      }
    }
  }
  else if (bid < 264) {
    // ---- cvec = bo @ W* + b*   (region 3: just bo) ----
    const int q = bid - 256;
    const int r2 = q >> 1;
    const float* Ws = (r2 == 0) ? Wr : (r2 == 1) ? Wz : (r2 == 2) ? Wh : nullptr;
    const float* bs = (r2 == 0) ? br : (r2 == 1) ? bz : (r2 == 2) ? bh : nullptr;
    for (int round = 0; round < 8; ++round) {
      int col32 = t >> 3, strip = t & 7;
      int c = q * 256 + round * 32 + col32;
      int cc = c & 511;
      float p = 0.f;
      if (r2 < 3) {
        for (int j = strip * 64; j < strip * 64 + 64; ++j)
          p = fmaf(bo[j], Ws[j * 512 + cc], p);
      }
      sh[col32 * 8 + strip] = p;
      __syncthreads();
      if (t < 32) {
        float v = 0.f;
        #pragma unroll
        for (int st = 0; st < 8; ++st) v += sh[t * 8 + st];
        int c2 = q * 256 + round * 32 + t;
        int cc2 = c2 & 511;
        cv[c2] = (r2 < 3) ? (v + bs[cc2]) : bo[cc2];
      }
      __syncthreads();
    }
  }
  else if (bid < 288) {
    // ---- M1 = [Wr|Wz|Wh] copy (chunks 0..95) ----
    const int q = bid - 264;
    for (int cq = 0; cq < 4; ++cq) {
      int ch = q * 4 + cq;
      int r3 = ch >> 5;
      const float* Ws = (r3 == 0) ? Wr : (r3 == 1) ? Wz : Wh;
      int cc0 = (ch & 31) * 16;
      for (int i = 0; i < 32; ++i) {
        int idx = t + i * 256;
        int kk = idx >> 4, ci = idx & 15;
        M1w[(ch * 512 + kk) * 16 + ci] = Ws[kk * 512 + cc0 + ci];
      }
    }
  }
  else if (bid < 296) {
    // ---- M1 Wo-part zero (chunks 96..127) ----
    const int q = bid - 288;
    for (int cq = 0; cq < 4; ++cq) {
      int ch = 96 + q * 4 + cq;
      for (int i = 0; i < 32; ++i) {
        int idx = t + i * 256;
        M1w[ch * 8192 + idx] = 0.f;
      }
    }
  }
  else if (bid < 312) {
    // ---- Uh reshape to [128 chunks][512 k][4 c] ----
    const int q = bid - 296;
    for (int cq = 0; cq < 8; ++cq) {
      int ch = q * 8 + cq;
      for (int i = 0; i < 8; ++i) {
        int idx = t + i * 256;
        int kk = idx >> 2, ci = idx & 3;
        Uhw[(ch * 512 + kk) * 4 + ci] = Uh[kk * 512 + ch * 4 + ci];
      }
    }
  }
  else if (bid < 316) {
    // ---- xT = inputs^T (64x64 LDS tiles) ----
    const int q = bid - 312;
    for (int ti = q * 4; ti < q * 4 + 4; ++ti) {
      int bt = ti >> 3, dt = ti & 7;
      __syncthreads();
      for (int i = 0; i < 16; ++i) {
        int idx = t + i * 256;
        int r = idx >> 6, c = idx & 63;
        sh[r * 65 + c] = inputs[(bt * 64 + r) * 512 + dt * 64 + c];
      }
      __syncthreads();
      for (int i = 0; i < 16; ++i) {
        int idx = t + i * 256;
        int r = idx >> 6, c = idx & 63;
        xT[(dt * 64 + r) * 128 + bt * 64 + c] = sh[c * 65 + r];
      }
    }
    if (q == 0) {
      for (int idx = t; idx < 16 * 128; idx += 256) xT[512 * 128 + idx] = 0.f;
    }
  }
  else if (bid == 316) {
    for (int idx = t; idx < ROWS * 128; idx += 256) hw[idx] = 0.f;     // h0 = 0 (+pads)
  }
  else if (bid == 317) {
    for (int idx = t; idx < 16 * 128; idx += 256) rhw[512 * 128 + idx] = 0.f;  // rh pads
  }
  else if (bid == 318) {
    for (int idx = t; idx < 2048; idx += 256)
      c1[idx] = (idx < 512) ? br[idx] : (idx < 1024) ? bz[idx - 512]
              : (idx < 1536) ? bh[idx - 1024] : 0.f;
    for (int idx = t; idx < 4096; idx += 256) bar[idx] = 0u;
  }
}

// ================ group-local barrier (fence-free, 128 blocks) ================
// Arrival: 16 blocks per (grp, xcls) class -> 8 classes per group -> release flags.
// Release: __syncthreads() drains vmcnt (coherent stores at L3 before arrival).
// Acquire: sc1 loads always read the coherence point.
__device__ __forceinline__ void gbar(uint32_t* bar, int grp, int xcls, uint32_t ph) {
  __syncthreads();
  if (threadIdx.x == 0) {
    const int cls = grp * 8 + xcls;
    uint32_t o = __hip_atomic_fetch_add(&bar[cls * 32], 1u, __ATOMIC_RELAXED, __HIP_MEMORY_SCOPE_AGENT);
    if (o == ph * 16u + 15u) {                    // last of this class
      uint32_t g = __hip_atomic_fetch_add(&bar[1024 + grp * 32], 1u, __ATOMIC_RELAXED, __HIP_MEMORY_SCOPE_AGENT);
      if (g == ph * 8u + 7u) {                    // last class of group
        #pragma unroll
        for (int x = 0; x < 8; ++x)
          __hip_atomic_store(&bar[2048 + (grp * 8 + x) * 32], ph + 1u, __ATOMIC_RELAXED, __HIP_MEMORY_SCOPE_AGENT);
      }
    }
    int guard = 0;
    while (__hip_atomic_load(&bar[2048 + cls * 32], __ATOMIC_RELAXED, __HIP_MEMORY_SCOPE_AGENT) < ph + 1u) {
      __builtin_amdgcn_s_sleep(1);
      if (++guard > (1 << 22)) break;             // anti-hang safety
    }
  }
  __syncthreads();
}

// ======================= persistent main kernel =======================
// 512 blocks x 512 threads, 2 blocks/CU. 4 independent batch-groups of 32,
// each a 128-block gang with group-local barriers. Co-resident blocks are
// from different groups -> barrier waits hide under the other group's compute.
// Phase A: block = chnk 0..127 (16 cols of [Ar|Az|Ah|Wo]); K=512 over 8 waves x 2 halves x 32.
// Phase B: block = chnk -> 4 cols of Uh; same K split.
__global__ __launch_bounds__(512, 4) void gru_main(
    const float* __restrict__ inputs,
    const float* __restrict__ Mw, const float* __restrict__ M1w,
    const float* __restrict__ Uhw,
    const float* __restrict__ cvec, const float* __restrict__ c1vec,
    float* __restrict__ hw, float* __restrict__ rhw,
    const float* __restrict__ xT,
    float* __restrict__ Gz, float* __restrict__ Gh,
    uint32_t* __restrict__ bar, float* __restrict__ out, const int T)
{
  __shared__ float Ald[8192];   // 32 KB  [512 k][16 c] A-weight slice
  __shared__ float Uld[2048];   //  8 KB  [512 k][4 c]  B-weight slice
  __shared__ float red[4224];   // 16.5 KB [8 waves][16 c][33] (padded)
  __shared__ float ttr[544];    //  2.1 KB [32 b][17]  out-transpose staging

  const int bid = blockIdx.x, tid = threadIdx.x;
  const int wave = __builtin_amdgcn_readfirstlane(tid >> 6);  // 0..7, scalar
  const int lane = tid & 63;
  const int kh = lane >> 5, bb = lane & 31;    // k-half, batch-in-group
  const int grp = bid >> 7, chnk = bid & 127;
  const int typ = chnk >> 5;                   // 0:r 1:z 2:h 3:out
  const int bo = grp * 32;                     // batch offset of this group
  const int xcls = bid & 7;
  const int k0 = wave * 64 + kh * 32;          // this half-wave's k range
  const int c2 = tid >> 5, b2 = tid & 31;      // stage-2 coords (16 c x 32 b)
  uint32_t ph = 0;

  // ---- initial stage: M1 slice + Uh slice into LDS ----
  {
    const float* src = M1w + (size_t)chnk * 8192;
    #pragma unroll
    for (int i = 0; i < 4; ++i) {
      const int idx4 = tid + i * 512;
      *(float4*)&Ald[idx4 * 4] = *(const float4*)&src[idx4 * 4];
    }
    *(float4*)&Uld[tid * 4] = *(const float4*)&Uhw[(size_t)chnk * 2048 + tid * 4];
  }
  __syncthreads();

  for (int s = 1; s <= T; ++s) {
    // ======== phase A : pre = src @ M (+bias), per-type epilogue ========
    {
      const float* hsrc = (s == 1) ? xT : hw;
      const float* cv = (s == 1) ? c1vec : cvec;
      // epilogue prefetch: typ0 needs h_prev (hide L3 latency under FMAs)
      float hpre = 0.f;
      if (typ == 0)
        hpre = cload(&hw[(chnk * 16 + c2) * 128 + bo + b2]);
      const float* hp = hsrc + k0 * 128 + bo + bb;
      float hv[32];
      #pragma unroll
      for (int u = 0; u < 32; ++u) hv[u] = cload(hp + u * 128);
      float acc[16];
      #pragma unroll
      for (int c = 0; c < 16; ++c) acc[c] = 0.f;
      #pragma unroll
      for (int u = 0; u < 32; ++u) {
        const float cur = hv[u];
        const float* mrow = &Ald[(k0 + u) * 16];   // half-wave-uniform LDS row
        #pragma unroll
        for (int c = 0; c < 16; ++c) acc[c] = fmaf(cur, mrow[c], acc[c]);
      }
      // combine k-halves within the wave, then 8-way LDS reduction
      #pragma unroll
      for (int c = 0; c < 16; ++c) acc[c] += __shfl_xor(acc[c], 32, 64);
      if (kh == 0) {
        #pragma unroll
        for (int c = 0; c < 16; ++c) red[wave * 528 + c * 33 + bb] = acc[c];
      }
      __syncthreads();
      float v = cv[chnk * 16 + c2];
      #pragma unroll
      for (int w = 0; w < 8; ++w) v += red[w * 528 + c2 * 33 + b2];
      const int cglob = chnk * 16 + c2;
      if (typ == 0) {               // r gate -> rh = sigmoid(pre) * h_prev
        cstore(&rhw[cglob * 128 + bo + b2], sigm(v) * hpre);
      } else if (typ == 1) {        // z gate (store activated)
        cstore(&Gz[(cglob - 512) * 128 + bo + b2], sigm(v));
      } else if (typ == 2) {        // pre-h (x part + bias)
        cstore(&Gh[(cglob - 1024) * 128 + bo + b2], v);
      } else if (s > 1) {           // out_{s-1} -> d_out[:, s-1, :] via LDS remap
        ttr[b2 * 17 + c2] = v;
        __syncthreads();
        const int bq = tid >> 4, dq = tid & 15;
        out[(size_t)(bo + bq) * (size_t)T * 512 + (size_t)(s - 1) * 512
            + (chnk - 96) * 16 + dq] = ttr[bq * 17 + dq];
      }
    }
    gbar(bar, grp, xcls, ph++);

    if (s < T) {
      if (s == 1) {
        // restage Ald with the folded M (used from s==2 on)
        const float* src = Mw + (size_t)chnk * 8192;
        #pragma unroll
        for (int i = 0; i < 4; ++i) {
          const int idx4 = tid + i * 512;
          *(float4*)&Ald[idx4 * 4] = *(const float4*)&src[idx4 * 4];
        }
        // out[:, 0, :] = inputs (512 blocks x 128 floats)
        if (tid < 128) {
          const int idx = bid * 128 + tid;
          out[(size_t)(idx >> 9) * (size_t)T * 512 + (idx & 511)] = inputs[idx];
        }
      }
      // ======== phase B : S = rh @ Uh ; h update ========
      {
        // epilogue prefetch: Gz/Gh/h_prev (hide L3 latency under FMAs)
        float zf = 0.f, ghf = 0.f, hprev = 0.f;
        if (tid < 128) {
          const int cg = chnk * 4 + (tid >> 5);
          zf    = cload(&Gz[cg * 128 + bo + b2]);
          ghf   = cload(&Gh[cg * 128 + bo + b2]);
          hprev = cload(&hw[cg * 128 + bo + b2]);
        }
        const float* rp = rhw + k0 * 128 + bo + bb;
        float hv[32];
        #pragma unroll
        for (int u = 0; u < 32; ++u) hv[u] = cload(rp + u * 128);
        float a2[4];
        #pragma unroll
        for (int c = 0; c < 4; ++c) a2[c] = 0.f;
        #pragma unroll
        for (int u = 0; u < 32; ++u) {
          const float cur = hv[u];
          const float* urow = &Uld[(k0 + u) * 4];
          #pragma unroll
          for (int c = 0; c < 4; ++c) a2[c] = fmaf(cur, urow[c], a2[c]);
        }
        #pragma unroll
        for (int c = 0; c < 4; ++c) a2[c] += __shfl_xor(a2[c], 32, 64);
        if (kh == 0) {
          #pragma unroll
          for (int c = 0; c < 4; ++c) red[wave * 132 + c * 33 + bb] = a2[c];
        }
        __syncthreads();
        if (tid < 128) {
          float S = 0.f;
          #pragma unroll
          for (int w = 0; w < 8; ++w) S += red[w * 132 + (tid >> 5) * 33 + b2];
          const int cg = chnk * 4 + (tid >> 5);
          float hn = (1.f - zf) * hprev + zf * tanh_fast(ghf + S);
          hn = fminf(5.f, fmaxf(-5.f, hn));
          cstore(&hw[cg * 128 + bo + b2], hn);
        }
      }
      gbar(bar, grp, xcls, ph++);
    }
  }
}

// ======================= host launcher =======================
extern "C" void kernel_launch(void* const* d_in, const int* in_sizes, int n_in,
                              void* d_out, int out_size, void* d_ws, size_t ws_size,
                              hipStream_t stream) {
  const float* inputs = (const float*)d_in[0];
  const float* Wz = (const float*)d_in[1];
  const float* Wr = (const float*)d_in[2];
  const float* Wh = (const float*)d_in[3];
  const float* Uz = (const float*)d_in[4];
  const float* Ur = (const float*)d_in[5];
  const float* Uh = (const float*)d_in[6];
  const float* bz = (const float*)d_in[7];
  const float* br = (const float*)d_in[8];
  const float* bh = (const float*)d_in[9];
  const float* Wo = (const float*)d_in[10];
  const float* bo = (const float*)d_in[11];
  float* ws = (float*)d_ws;
  const int T = out_size / (128 * 512);

  gru_pre<<<dim3(320), dim3(256), 0, stream>>>(inputs, Wz, Wr, Wh, Uz, Ur, Uh,
                                               bz, br, bh, Wo, bo, ws);
  gru_main<<<dim3(512), dim3(512), 0, stream>>>(
      inputs, ws + OFF_M, ws + OFF_M1, ws + OFF_UH, ws + OFF_CV, ws + OFF_C1,
      ws + OFF_H, ws + OFF_RH, ws + OFF_XT, ws + OFF_GZ, ws + OFF_GH,
      (uint32_t*)(ws + OFF_BAR), (float*)d_out, T);
}

// Round 5
// 8317.309 us; speedup vs baseline: 1.4750x; 1.4750x over previous
//
#include <hip/hip_runtime.h>
#include <cstdint>

#define NB 128      // batch
#define DH 512      // D == H
#define ROWS 528    // DH + 16 pad rows (legacy safety margin)

// ---- workspace layout (float offsets) ----
#define OFF_M   0u          // [128 chunks][512 k][16 c]  folded [Ar|Az|Ah|Wo]
#define OFF_M1  1048576u    // [128][512][16]             step-1 [Wr|Wz|Wh|0]
#define OFF_UH  2097152u    // [128 chunks][512 k][4 c]   Uh
#define OFF_H   2359296u    // [528][128]  h (transposed, padded)
#define OFF_RH  2426880u    // [528][128]  r*h
#define OFF_XT  2494464u    // [528][128]  inputs^T
#define OFF_GZ  2562048u    // [512][128]  z gate (activated)
#define OFF_GH  2627584u    // [512][128]  pre-h (x-part + bias)
#define OFF_CV  2693120u    // [2048] folded biases
#define OFF_C1  2695168u    // [2048] step-1 biases
#define OFF_BAR 2697216u    // 4096 uint32 barrier state

__device__ __forceinline__ float sigm(float x) { return 1.f / (1.f + __expf(-x)); }
__device__ __forceinline__ float tanh_fast(float x) {
  float e = __expf(2.f * fminf(x, 40.f));
  return (e - 1.f) / (e + 1.f);
}

// Coherent (agent-scope) access -> global_load/store sc0 sc1: always served at
// the coherence point; no cache-wide fences needed anywhere.
__device__ __forceinline__ float cload(const float* p) {
  return __hip_atomic_load(p, __ATOMIC_RELAXED, __HIP_MEMORY_SCOPE_AGENT);
}
__device__ __forceinline__ void cstore(float* p, float v) {
  __hip_atomic_store(p, v, __ATOMIC_RELAXED, __HIP_MEMORY_SCOPE_AGENT);
}

// ======================= precompute kernel =======================
__global__ __launch_bounds__(256) void gru_pre(
    const float* __restrict__ inputs,
    const float* __restrict__ Wz, const float* __restrict__ Wr, const float* __restrict__ Wh,
    const float* __restrict__ Uz, const float* __restrict__ Ur, const float* __restrict__ Uh,
    const float* __restrict__ bz, const float* __restrict__ br, const float* __restrict__ bh,
    const float* __restrict__ Wo, const float* __restrict__ bo,
    float* __restrict__ ws)
{
  __shared__ float sh[8960];            // 35 KB scratch, reused per task
  const int bid = blockIdx.x, t = threadIdx.x;
  float* Mw  = ws + OFF_M;
  float* M1w = ws + OFF_M1;
  float* Uhw = ws + OFF_UH;
  float* hw  = ws + OFF_H;
  float* rhw = ws + OFF_RH;
  float* xT  = ws + OFF_XT;
  float* cv  = ws + OFF_CV;
  float* c1  = ws + OFF_C1;
  uint32_t* bar = (uint32_t*)(ws + OFF_BAR);

  if (bid < 256) {
    // ---- build M = [Wo@Wr+Ur | Wo@Wz+Uz | Wo@Wh | Wo] ----
    const int kh = bid >> 7, cch = bid & 127;
    const int reg = cch >> 5;
    const int k0 = kh * 256, c0 = cch * 16;
    if (reg == 3) {
      const int cc0 = c0 - 1536;
      for (int i = 0; i < 16; ++i) {
        int idx = t + i * 256;
        int kk = k0 + (idx >> 4), ci = idx & 15;
        Mw[(cch * 512 + kk) * 16 + ci] = Wo[kk * 512 + cc0 + ci];
      }
    } else {
      const float* Ws = (reg == 0) ? Wr : (reg == 1) ? Wz : Wh;
      const float* Us = (reg == 0) ? Ur : (reg == 1) ? Uz : nullptr;
      const int cc0 = c0 - reg * 512;
      const int kl = t;                 // 256 threads <-> 256 local k rows
      const int k = k0 + kl;
      float acc[16];
      #pragma unroll
      for (int c = 0; c < 16; ++c) acc[c] = 0.f;
      for (int jt = 0; jt < 16; ++jt) {          // 32-wide j tiles of Wo
        __syncthreads();
        for (int i = 0; i < 32; ++i) {
          int idx = t + i * 256;                 // 8192 = 256k x 32j
          int kk = idx >> 5, jj = idx & 31;
          sh[kk * 35 + jj] = Wo[(k0 + kk) * 512 + jt * 32 + jj];
        }
        __syncthreads();
        for (int j = 0; j < 32; ++j) {
          float wv = sh[kl * 35 + j];
          const float* wrow = Ws + (jt * 32 + j) * 512 + cc0;
          #pragma unroll
          for (int c = 0; c < 16; ++c) acc[c] = fmaf(wv, wrow[c], acc[c]);
        }
      }
      #pragma unroll
      for (int c = 0; c < 16; ++c) {
        float v = acc[c];
        if (Us) v += Us[k * 512 + cc0 + c];
        Mw[(cch * 512 + k) * 16 + c] = v;
      }
    }
  }
  else if (bid < 264) {
    // ---- cvec = bo @ W* + b*   (region 3: just bo) ----
    const int q = bid - 256;
    const int r2 = q >> 1;
    const float* Ws = (r2 == 0) ? Wr : (r2 == 1) ? Wz : (r2 == 2) ? Wh : nullptr;
    const float* bs = (r2 == 0) ? br : (r2 == 1) ? bz : (r2 == 2) ? bh : nullptr;
    for (int round = 0; round < 8; ++round) {
      int col32 = t >> 3, strip = t & 7;
      int c = q * 256 + round * 32 + col32;
      int cc = c & 511;
      float p = 0.f;
      if (r2 < 3) {
        for (int j = strip * 64; j < strip * 64 + 64; ++j)
          p = fmaf(bo[j], Ws[j * 512 + cc], p);
      }
      sh[col32 * 8 + strip] = p;
      __syncthreads();
      if (t < 32) {
        float v = 0.f;
        #pragma unroll
        for (int st = 0; st < 8; ++st) v += sh[t * 8 + st];
        int c2 = q * 256 + round * 32 + t;
        int cc2 = c2 & 511;
        cv[c2] = (r2 < 3) ? (v + bs[cc2]) : bo[cc2];
      }
      __syncthreads();
    }
  }
  else if (bid < 288) {
    // ---- M1 = [Wr|Wz|Wh] copy (chunks 0..95) ----
    const int q = bid - 264;
    for (int cq = 0; cq < 4; ++cq) {
      int ch = q * 4 + cq;
      int r3 = ch >> 5;
      const float* Ws = (r3 == 0) ? Wr : (r3 == 1) ? Wz : Wh;
      int cc0 = (ch & 31) * 16;
      for (int i = 0; i < 32; ++i) {
        int idx = t + i * 256;
        int kk = idx >> 4, ci = idx & 15;
        M1w[(ch * 512 + kk) * 16 + ci] = Ws[kk * 512 + cc0 + ci];
      }
    }
  }
  else if (bid < 296) {
    // ---- M1 Wo-part zero (chunks 96..127) ----
    const int q = bid - 288;
    for (int cq = 0; cq < 4; ++cq) {
      int ch = 96 + q * 4 + cq;
      for (int i = 0; i < 32; ++i) {
        int idx = t + i * 256;
        M1w[ch * 8192 + idx] = 0.f;
      }
    }
  }
  else if (bid < 312) {
    // ---- Uh reshape to [128 chunks][512 k][4 c] ----
    const int q = bid - 296;
    for (int cq = 0; cq < 8; ++cq) {
      int ch = q * 8 + cq;
      for (int i = 0; i < 8; ++i) {
        int idx = t + i * 256;
        int kk = idx >> 2, ci = idx & 3;
        Uhw[(ch * 512 + kk) * 4 + ci] = Uh[kk * 512 + ch * 4 + ci];
      }
    }
  }
  else if (bid < 316) {
    // ---- xT = inputs^T (64x64 LDS tiles) ----
    const int q = bid - 312;
    for (int ti = q * 4; ti < q * 4 + 4; ++ti) {
      int bt = ti >> 3, dt = ti & 7;
      __syncthreads();
      for (int i = 0; i < 16; ++i) {
        int idx = t + i * 256;
        int r = idx >> 6, c = idx & 63;
        sh[r * 65 + c] = inputs[(bt * 64 + r) * 512 + dt * 64 + c];
      }
      __syncthreads();
      for (int i = 0; i < 16; ++i) {
        int idx = t + i * 256;
        int r = idx >> 6, c = idx & 63;
        xT[(dt * 64 + r) * 128 + bt * 64 + c] = sh[c * 65 + r];
      }
    }
    if (q == 0) {
      for (int idx = t; idx < 16 * 128; idx += 256) xT[512 * 128 + idx] = 0.f;
    }
  }
  else if (bid == 316) {
    for (int idx = t; idx < ROWS * 128; idx += 256) hw[idx] = 0.f;     // h0 = 0 (+pads)
  }
  else if (bid == 317) {
    for (int idx = t; idx < 16 * 128; idx += 256) rhw[512 * 128 + idx] = 0.f;  // rh pads
  }
  else if (bid == 318) {
    for (int idx = t; idx < 2048; idx += 256)
      c1[idx] = (idx < 512) ? br[idx] : (idx < 1024) ? bz[idx - 512]
              : (idx < 1536) ? bh[idx - 1024] : 0.f;
    for (int idx = t; idx < 4096; idx += 256) bar[idx] = 0u;
  }
}

// =============== flattened global barrier (fence-free) ===============
// Arrival: one block-leader atomic add to a single counter (after __syncthreads
// drained all waves' coherent stores). 256th arriver writes 8 padded flag lines.
// Wait: EVERY wave polls its flag line (uniform 64-lane load) and proceeds
// independently — no trailing __syncthreads; the next phase's internal sync
// re-converges the block.
__device__ __forceinline__ void gbar_arrive(uint32_t* bar, uint32_t ph) {
  __syncthreads();
  if (threadIdx.x == 0) {
    uint32_t g = __hip_atomic_fetch_add(&bar[0], 1u, __ATOMIC_RELAXED, __HIP_MEMORY_SCOPE_AGENT);
    if (g == ph * 256u + 255u) {
      #pragma unroll
      for (int x = 0; x < 8; ++x)
        __hip_atomic_store(&bar[64 + x * 32], ph + 1u, __ATOMIC_RELAXED, __HIP_MEMORY_SCOPE_AGENT);
    }
  }
}
__device__ __forceinline__ void gbar_wait(uint32_t* bar, int xcls, uint32_t ph) {
  int guard = 0;
  while (__hip_atomic_load(&bar[64 + xcls * 32], __ATOMIC_RELAXED, __HIP_MEMORY_SCOPE_AGENT) < ph + 1u) {
    __builtin_amdgcn_s_sleep(1);
    if (++guard > (1 << 22)) break;               // anti-hang safety
  }
}

// ======================= persistent main kernel =======================
// 256 blocks x 512 threads (8 waves), 1 block/CU. Weights in LDS; cross-block
// state via agent-coherent loads/stores (proven R3 structure).
// Phase A: block = (bh 0..1) x (chnk 0..127 -> 16 cols); K=512 over 8 waves x 64.
// Phase B: block = (bh 0..1) x (ch4 0..127 -> 4 cols);  K=512 over 8 waves x 64.
__global__ __launch_bounds__(512, 2) void gru_main(
    const float* __restrict__ inputs,
    const float* __restrict__ Mw, const float* __restrict__ M1w,
    const float* __restrict__ Uhw,
    const float* __restrict__ cvec, const float* __restrict__ c1vec,
    float* __restrict__ hw, float* __restrict__ rhw,
    const float* __restrict__ xT,
    float* __restrict__ Gz, float* __restrict__ Gh,
    uint32_t* __restrict__ bar, float* __restrict__ out, const int T)
{
  __shared__ float Ald[8192];   // 32 KB  [512 k][16 c] A-weight slice
  __shared__ float Uld[2048];   //  8 KB  [512 k][4 c]  B-weight slice
  __shared__ float red[4096];   // 16 KB  cross-wave reduction
  __shared__ float ttr[1024];   //  4 KB  [64 b][16 d] out-transpose staging

  const int bid = blockIdx.x, tid = threadIdx.x;
  const int wave = __builtin_amdgcn_readfirstlane(tid >> 6);  // 0..7, scalar
  const int lane = tid & 63;
  const int bh = bid >> 7, chnk = bid & 127;   // phase-A coords
  const int typ = chnk >> 5;                   // 0:r 1:z 2:h 3:out
  const int b = bh * 64 + lane;
  const int xcls = bid & 7;
  uint32_t ph = 0;

  // ---- initial stage: M1 slice + Uh slice into LDS ----
  {
    const float* src = M1w + (size_t)chnk * 8192;
    #pragma unroll
    for (int i = 0; i < 4; ++i) {
      const int idx4 = tid + i * 512;
      *(float4*)&Ald[idx4 * 4] = *(const float4*)&src[idx4 * 4];
    }
    *(float4*)&Uld[tid * 4] = ((const float4*)(Uhw + (size_t)chnk * 2048))[tid];
  }
  __syncthreads();

  for (int s = 1; s <= T; ++s) {
    // ======== phase A : pre = src @ M (+bias), per-type epilogue ========
    {
      const float* hsrc = (s == 1) ? xT : hw;
      const float* cv = (s == 1) ? c1vec : cvec;
      float acc[16];
      #pragma unroll
      for (int c = 0; c < 16; ++c) acc[c] = 0.f;
      const float* hp = hsrc + (wave * 64) * 128 + b;
      float hv[32];
      #pragma unroll
      for (int u = 0; u < 32; ++u) hv[u] = cload(hp + u * 128);
      #pragma unroll
      for (int u = 0; u < 32; ++u) {              // consume rows 0..31, prefetch 32..63
        const float cur = hv[u];
        hv[u] = cload(hp + (32 + u) * 128);
        const float* mrow = &Ald[(wave * 64 + u) * 16];
        #pragma unroll
        for (int c = 0; c < 16; ++c) acc[c] = fmaf(cur, mrow[c], acc[c]);
      }
      #pragma unroll
      for (int u = 0; u < 32; ++u) {              // peeled tail: rows 32..63
        const float* mrow = &Ald[(wave * 64 + 32 + u) * 16];
        #pragma unroll
        for (int c = 0; c < 16; ++c) acc[c] = fmaf(hv[u], mrow[c], acc[c]);
      }
      // two-stage cross-wave reduction (8 -> 4 -> epilogue)
      if (wave >= 4) {
        #pragma unroll
        for (int c = 0; c < 16; ++c) red[((wave - 4) * 16 + c) * 64 + lane] = acc[c];
      }
      __syncthreads();
      if (wave < 4) {
        #pragma unroll
        for (int c = 0; c < 16; ++c) red[(wave * 16 + c) * 64 + lane] += acc[c];
      }
      __syncthreads();
      const int cg = tid >> 6, lane_ = tid & 63;
      const int bb = bh * 64 + lane_;
      float vout[2];
      #pragma unroll
      for (int i = 0; i < 2; ++i) {
        const int c = cg * 2 + i;
        float v = red[c * 64 + lane_] + red[(16 + c) * 64 + lane_]
                + red[(32 + c) * 64 + lane_] + red[(48 + c) * 64 + lane_];
        vout[i] = v + cv[chnk * 16 + c];
      }
      if (typ < 3) {
        if (typ == 0) {               // r gate -> rh = sigmoid(pre) * h_prev
          #pragma unroll
          for (int i = 0; i < 2; ++i) {
            const int cglob = chnk * 16 + cg * 2 + i;
            cstore(&rhw[cglob * 128 + bb], sigm(vout[i]) * cload(&hw[cglob * 128 + bb]));
          }
        } else if (typ == 1) {        // z gate (store activated)
          #pragma unroll
          for (int i = 0; i < 2; ++i) {
            const int cglob = chnk * 16 + cg * 2 + i;
            cstore(&Gz[(cglob - 512) * 128 + bb], sigm(vout[i]));
          }
        } else {                      // pre-h (x part + bias)
          #pragma unroll
          for (int i = 0; i < 2; ++i) {
            const int cglob = chnk * 16 + cg * 2 + i;
            cstore(&Gh[(cglob - 1024) * 128 + bb], vout[i]);
          }
        }
        gbar_arrive(bar, ph);
      } else {
        // out blocks: no coherent stores -> arrive FIRST, then store d_out
        // overlapped with everyone else's barrier wait.
        gbar_arrive(bar, ph);
        if (s > 1) {
          #pragma unroll
          for (int i = 0; i < 2; ++i) ttr[lane_ * 16 + cg * 2 + i] = vout[i];
          __syncthreads();
          const int bq = tid >> 3, pr = tid & 7;
          const float2 o2 = *(const float2*)&ttr[bq * 16 + pr * 2];
          const int bglob = bh * 64 + bq;
          const int d0 = (chnk - 96) * 16 + pr * 2;
          *(float2*)&out[(size_t)bglob * (size_t)T * 512 + (size_t)(s - 1) * 512 + d0] = o2;
        }
      }
    }
    gbar_wait(bar, xcls, ph); ++ph;

    if (s < T) {
      if (s == 1) {
        // restage Ald with the folded M (used from s==2 on).
        // Safe: every wave of every block has passed phase-A's arrive-sync,
        // so no Ald reads are in flight; next A reads gated by this phase's flag.
        const float* src = Mw + (size_t)chnk * 8192;
        #pragma unroll
        for (int i = 0; i < 4; ++i) {
          const int idx4 = tid + i * 512;
          *(float4*)&Ald[idx4 * 4] = *(const float4*)&src[idx4 * 4];
        }
        // out[:, 0, :] = inputs (256 blocks x 256 floats)
        if (tid < 256) {
          const int g = bid * 256 + tid;
          out[(size_t)(g >> 9) * (size_t)T * 512 + (g & 511)] = inputs[g];
        }
      }
      // ======== phase B : S = rh @ Uh ; h update (all 256 blocks, 4 cols) ========
      {
        const int ch4 = chnk;                    // 4-col chunk id (0..127)
        // epilogue prefetch: Gz/Gh/h_prev (hide L3 latency under FMAs)
        float zf = 0.f, ghf = 0.f, hprev = 0.f;
        const int c_loc = tid >> 6, bb3 = tid & 63;
        if (c_loc < 4) {
          const int cg2 = ch4 * 4 + c_loc;
          zf    = cload(&Gz[cg2 * 128 + bh * 64 + bb3]);
          ghf   = cload(&Gh[cg2 * 128 + bh * 64 + bb3]);
          hprev = cload(&hw[cg2 * 128 + bh * 64 + bb3]);
        }
        const float* rp = rhw + (wave * 64) * 128 + b;
        float hv[32];
        #pragma unroll
        for (int u = 0; u < 32; ++u) hv[u] = cload(rp + u * 128);
        float a2[4];
        #pragma unroll
        for (int c = 0; c < 4; ++c) a2[c] = 0.f;
        #pragma unroll
        for (int u = 0; u < 32; ++u) {
          const float cur = hv[u];
          hv[u] = cload(rp + (32 + u) * 128);
          const float* urow = &Uld[(wave * 64 + u) * 4];
          #pragma unroll
          for (int c = 0; c < 4; ++c) a2[c] = fmaf(cur, urow[c], a2[c]);
        }
        #pragma unroll
        for (int u = 0; u < 32; ++u) {
          const float* urow = &Uld[(wave * 64 + 32 + u) * 4];
          #pragma unroll
          for (int c = 0; c < 4; ++c) a2[c] = fmaf(hv[u], urow[c], a2[c]);
        }
        if (wave >= 4) {
          #pragma unroll
          for (int c = 0; c < 4; ++c) red[((wave - 4) * 4 + c) * 64 + lane] = a2[c];
        }
        __syncthreads();
        if (wave < 4) {
          #pragma unroll
          for (int c = 0; c < 4; ++c) red[(wave * 4 + c) * 64 + lane] += a2[c];
        }
        __syncthreads();
        if (c_loc < 4) {
          const float S = red[(c_loc) * 64 + bb3]      + red[(4 + c_loc) * 64 + bb3]
                        + red[(8 + c_loc) * 64 + bb3]  + red[(12 + c_loc) * 64 + bb3];
          const int cg2 = ch4 * 4 + c_loc;
          float hn = (1.f - zf) * hprev + zf * tanh_fast(ghf + S);
          hn = fminf(5.f, fmaxf(-5.f, hn));
          cstore(&hw[cg2 * 128 + bh * 64 + bb3], hn);
        }
        gbar_arrive(bar, ph);
      }
      gbar_wait(bar, xcls, ph); ++ph;
    }
  }
}

// ======================= host launcher =======================
extern "C" void kernel_launch(void* const* d_in, const int* in_sizes, int n_in,
                              void* d_out, int out_size, void* d_ws, size_t ws_size,
                              hipStream_t stream) {
  const float* inputs = (const float*)d_in[0];
  const float* Wz = (const float*)d_in[1];
  const float* Wr = (const float*)d_in[2];
  const float* Wh = (const float*)d_in[3];
  const float* Uz = (const float*)d_in[4];
  const float* Ur = (const float*)d_in[5];
  const float* Uh = (const float*)d_in[6];
  const float* bz = (const float*)d_in[7];
  const float* br = (const float*)d_in[8];
  const float* bh = (const float*)d_in[9];
  const float* Wo = (const float*)d_in[10];
  const float* bo = (const float*)d_in[11];
  float* ws = (float*)d_ws;
  const int T = out_size / (128 * 512);

  gru_pre<<<dim3(320), dim3(256), 0, stream>>>(inputs, Wz, Wr, Wh, Uz, Ur, Uh,
                                               bz, br, bh, Wo, bo, ws);
  gru_main<<<dim3(256), dim3(512), 0, stream>>>(
      inputs, ws + OFF_M, ws + OFF_M1, ws + OFF_UH, ws + OFF_CV, ws + OFF_C1,
      ws + OFF_H, ws + OFF_RH, ws + OFF_XT, ws + OFF_GZ, ws + OFF_GH,
      (uint32_t*)(ws + OFF_BAR), (float*)d_out, T);
}

// Round 9
// 6969.471 us; speedup vs baseline: 1.7603x; 1.1934x over previous
//
#include <hip/hip_runtime.h>
#include <cstdint>

#define NB 128      // batch
#define DH 512      // D == H
#define ROWS 528    // DH + 16 pad rows (legacy safety margin)

// ---- workspace layout (float offsets) ----
#define OFF_M   0u          // [128 chunks][512 k][16 c]  folded [Ar|Az|Ah|Wo]
#define OFF_M1  1048576u    // [128][512][16]             step-1 [Wr|Wz|Wh|0]
#define OFF_UH  2097152u    // [64 chunks][512 k][8 c]    Uh
#define OFF_H   2359296u    // [528][128]  h buffer 0 (transposed, padded)
#define OFF_RH  2426880u    // [528][128]  r*h
#define OFF_XT  2494464u    // [528][128]  inputs^T
#define OFF_GZ  2562048u    // [512][128]  z gate (activated)
#define OFF_GH  2627584u    // [512][128]  pre-h (x-part + bias)
#define OFF_CV  2693120u    // [2048] folded biases
#define OFF_C1  2695168u    // [2048] step-1 biases
#define OFF_BAR 2697216u    // 4096 uint32 barrier state (3 regions x 768, 128B-padded)
#define OFF_H2  2701312u    // [528][128]  h buffer 1

__device__ __forceinline__ float sigm(float x) { return 1.f / (1.f + __expf(-x)); }
__device__ __forceinline__ float tanh_fast(float x) {
  float e = __expf(2.f * fminf(x, 40.f));
  return (e - 1.f) / (e + 1.f);
}

// Coherent (agent-scope) access -> global_load/store sc0 sc1: always served at
// the coherence point; no cache-wide fences needed anywhere.
__device__ __forceinline__ float cload(const float* p) {
  return __hip_atomic_load(p, __ATOMIC_RELAXED, __HIP_MEMORY_SCOPE_AGENT);
}
__device__ __forceinline__ void cstore(float* p, float v) {
  __hip_atomic_store(p, v, __ATOMIC_RELAXED, __HIP_MEMORY_SCOPE_AGENT);
}

// ======================= precompute kernel =======================
__global__ __launch_bounds__(256) void gru_pre(
    const float* __restrict__ inputs,
    const float* __restrict__ Wz, const float* __restrict__ Wr, const float* __restrict__ Wh,
    const float* __restrict__ Uz, const float* __restrict__ Ur, const float* __restrict__ Uh,
    const float* __restrict__ bz, const float* __restrict__ br, const float* __restrict__ bh,
    const float* __restrict__ Wo, const float* __restrict__ bo,
    float* __restrict__ ws)
{
  __shared__ float sh[8960];            // 35 KB scratch, reused per task
  const int bid = blockIdx.x, t = threadIdx.x;
  float* Mw  = ws + OFF_M;
  float* M1w = ws + OFF_M1;
  float* Uhw = ws + OFF_UH;
  float* hw0 = ws + OFF_H;
  float* hw1 = ws + OFF_H2;
  float* rhw = ws + OFF_RH;
  float* xT  = ws + OFF_XT;
  float* cv  = ws + OFF_CV;
  float* c1  = ws + OFF_C1;
  uint32_t* bar = (uint32_t*)(ws + OFF_BAR);

  if (bid < 256) {
    // ---- build M = [Wo@Wr+Ur | Wo@Wz+Uz | Wo@Wh | Wo] ----
    const int kh = bid >> 7, cch = bid & 127;
    const int reg = cch >> 5;
    const int k0 = kh * 256, c0 = cch * 16;
    if (reg == 3) {
      const int cc0 = c0 - 1536;
      for (int i = 0; i < 16; ++i) {
        int idx = t + i * 256;
        int kk = k0 + (idx >> 4), ci = idx & 15;
        Mw[(cch * 512 + kk) * 16 + ci] = Wo[kk * 512 + cc0 + ci];
      }
    } else {
      const float* Ws = (reg == 0) ? Wr : (reg == 1) ? Wz : Wh;
      const float* Us = (reg == 0) ? Ur : (reg == 1) ? Uz : nullptr;
      const int cc0 = c0 - reg * 512;
      const int kl = t;                 // 256 threads <-> 256 local k rows
      const int k = k0 + kl;
      float acc[16];
      #pragma unroll
      for (int c = 0; c < 16; ++c) acc[c] = 0.f;
      for (int jt = 0; jt < 16; ++jt) {          // 32-wide j tiles of Wo
        __syncthreads();
        for (int i = 0; i < 32; ++i) {
          int idx = t + i * 256;                 // 8192 = 256k x 32j
          int kk = idx >> 5, jj = idx & 31;
          sh[kk * 35 + jj] = Wo[(k0 + kk) * 512 + jt * 32 + jj];
        }
        __syncthreads();
        for (int j = 0; j < 32; ++j) {
          float wv = sh[kl * 35 + j];
          const float* wrow = Ws + (jt * 32 + j) * 512 + cc0;
          #pragma unroll
          for (int c = 0; c < 16; ++c) acc[c] = fmaf(wv, wrow[c], acc[c]);
        }
      }
      #pragma unroll
      for (int c = 0; c < 16; ++c) {
        float v = acc[c];
        if (Us) v += Us[k * 512 + cc0 + c];
        Mw[(cch * 512 + k) * 16 + c] = v;
      }
    }
  }
  else if (bid < 264) {
    // ---- cvec = bo @ W* + b*   (region 3: just bo) ----
    const int q = bid - 256;
    const int r2 = q >> 1;
    const float* Ws = (r2 == 0) ? Wr : (r2 == 1) ? Wz : (r2 == 2) ? Wh : nullptr;
    const float* bs = (r2 == 0) ? br : (r2 == 1) ? bz : (r2 == 2) ? bh : nullptr;
    for (int round = 0; round < 8; ++round) {
      int col32 = t >> 3, strip = t & 7;
      int c = q * 256 + round * 32 + col32;
      int cc = c & 511;
      float p = 0.f;
      if (r2 < 3) {
        for (int j = strip * 64; j < strip * 64 + 64; ++j)
          p = fmaf(bo[j], Ws[j * 512 + cc], p);
      }
      sh[col32 * 8 + strip] = p;
      __syncthreads();
      if (t < 32) {
        float v = 0.f;
        #pragma unroll
        for (int st = 0; st < 8; ++st) v += sh[t * 8 + st];
        int c2 = q * 256 + round * 32 + t;
        int cc2 = c2 & 511;
        cv[c2] = (r2 < 3) ? (v + bs[cc2]) : bo[cc2];
      }
      __syncthreads();
    }
  }
  else if (bid < 288) {
    // ---- M1 = [Wr|Wz|Wh] copy (chunks 0..95) ----
    const int q = bid - 264;
    for (int cq = 0; cq < 4; ++cq) {
      int ch = q * 4 + cq;
      int r3 = ch >> 5;
      const float* Ws = (r3 == 0) ? Wr : (r3 == 1) ? Wz : Wh;
      int cc0 = (ch & 31) * 16;
      for (int i = 0; i < 32; ++i) {
        int idx = t + i * 256;
        int kk = idx >> 4, ci = idx & 15;
        M1w[(ch * 512 + kk) * 16 + ci] = Ws[kk * 512 + cc0 + ci];
      }
    }
  }
  else if (bid < 296) {
    // ---- M1 Wo-part zero (chunks 96..127) ----
    const int q = bid - 288;
    for (int cq = 0; cq < 4; ++cq) {
      int ch = 96 + q * 4 + cq;
      for (int i = 0; i < 32; ++i) {
        int idx = t + i * 256;
        M1w[ch * 8192 + idx] = 0.f;
      }
    }
  }
  else if (bid < 312) {
    // ---- Uh reshape to [64 chunks][512 k][8 c] ----
    const int q = bid - 296;
    for (int cq = 0; cq < 4; ++cq) {
      int ch = q * 4 + cq;
      for (int i = 0; i < 16; ++i) {
        int idx = t + i * 256;
        int kk = idx >> 3, ci = idx & 7;
        Uhw[(ch * 512 + kk) * 8 + ci] = Uh[kk * 512 + ch * 8 + ci];
      }
    }
  }
  else if (bid < 316) {
    // ---- xT = inputs^T (64x64 LDS tiles) ----
    const int q = bid - 312;
    for (int ti = q * 4; ti < q * 4 + 4; ++ti) {
      int bt = ti >> 3, dt = ti & 7;
      __syncthreads();
      for (int i = 0; i < 16; ++i) {
        int idx = t + i * 256;
        int r = idx >> 6, c = idx & 63;
        sh[r * 65 + c] = inputs[(bt * 64 + r) * 512 + dt * 64 + c];
      }
      __syncthreads();
      for (int i = 0; i < 16; ++i) {
        int idx = t + i * 256;
        int r = idx >> 6, c = idx & 63;
        xT[(dt * 64 + r) * 128 + bt * 64 + c] = sh[c * 65 + r];
      }
    }
    if (q == 0) {
      for (int idx = t; idx < 16 * 128; idx += 256) xT[512 * 128 + idx] = 0.f;
    }
  }
  else if (bid == 316) {
    for (int idx = t; idx < ROWS * 128; idx += 256) hw0[idx] = 0.f;    // h buf0 = 0
  }
  else if (bid == 317) {
    for (int idx = t; idx < 16 * 128; idx += 256) rhw[512 * 128 + idx] = 0.f;  // rh pads
  }
  else if (bid == 318) {
    for (int idx = t; idx < 2048; idx += 256)
      c1[idx] = (idx < 512) ? br[idx] : (idx < 1024) ? bz[idx - 512]
              : (idx < 1536) ? bh[idx - 1024] : 0.f;
    for (int idx = t; idx < 4096; idx += 256) bar[idx] = 0u;
  }
  else if (bid == 319) {
    for (int idx = t; idx < ROWS * 128; idx += 256) hw1[idx] = 0.f;    // h buf1 = 0
  }
}

// =============== partial barriers (fence-free, two-level) ===============
// Region layout (uint32): base+cls*32 (8 class counters), base+256 (global),
// base+512+cls*32 (8 release-flag lines). Regions: R=0, G=1024, B=2048.
// Release: arrive()'s __syncthreads drains the block's coherent stores first.
// Acquire: sc1 loads always read the coherence point.
#define BAR_R 0
#define BAR_G 1024
#define BAR_B 2048

__device__ __forceinline__ void arrive(uint32_t* bar, int base, int xcls,
                                       uint32_t perCls, uint32_t ph) {
  __syncthreads();
  if (threadIdx.x == 0) {
    uint32_t o = __hip_atomic_fetch_add(&bar[base + xcls * 32], 1u,
                                        __ATOMIC_RELAXED, __HIP_MEMORY_SCOPE_AGENT);
    if (o == ph * perCls + (perCls - 1u)) {
      uint32_t g = __hip_atomic_fetch_add(&bar[base + 256], 1u,
                                          __ATOMIC_RELAXED, __HIP_MEMORY_SCOPE_AGENT);
      if (g == ph * 8u + 7u) {
        #pragma unroll
        for (int x = 0; x < 8; ++x)
          __hip_atomic_store(&bar[base + 512 + x * 32], ph + 1u,
                             __ATOMIC_RELAXED, __HIP_MEMORY_SCOPE_AGENT);
      }
    }
  }
}
__device__ __forceinline__ void waitf(uint32_t* bar, int base, int xcls, uint32_t ph) {
  if (threadIdx.x == 0) {
    int guard = 0;
    while (__hip_atomic_load(&bar[base + 512 + xcls * 32],
                             __ATOMIC_RELAXED, __HIP_MEMORY_SCOPE_AGENT) < ph + 1u) {
      __builtin_amdgcn_s_sleep(1);
      if (++guard > (1 << 18)) break;             // anti-hang: ~7ms then proceed
    }
  }
  __syncthreads();
}

// ======================= persistent main kernel =======================
// 256 blocks x 512 threads (8 waves), 1 block/CU. Weights in LDS; cross-block
// state via agent-coherent loads/stores. h is DOUBLE-BUFFERED (read h[s&1],
// write h[(s+1)&1]) which removes the WAR hazard and enables partial barriers:
//   flag_r : 64 typ0 arrivals  -> releases B matmul (rh RAW)
//   flag_g : 192 typ1/2/3 arrivals -> gates B epilogue (Gz/Gh RAW + h-read WAR)
//   flag_b : 128 B-block arrivals  -> releases step s+1 (h RAW)
// Chain B(s+1) => flag_r(s+1) => typ0 passed flag_b(s) => B(s) done => flag_g(s)
// => all step-s h readers done, so no reader can see a premature overwrite.
__global__ __launch_bounds__(512, 2) void gru_main(
    const float* __restrict__ inputs,
    const float* __restrict__ Mw, const float* __restrict__ M1w,
    const float* __restrict__ Uhw,
    const float* __restrict__ cvec, const float* __restrict__ c1vec,
    float* __restrict__ hw0, float* __restrict__ hw1,
    float* __restrict__ rhw,
    const float* __restrict__ xT,
    float* __restrict__ Gz, float* __restrict__ Gh,
    uint32_t* __restrict__ bar, float* __restrict__ out, const int T)
{
  __shared__ float Ald[8192];   // 32 KB  [512 k][16 c] A-weight slice
  __shared__ float Uld[4096];   // 16 KB  [512 k][8 c]  B-weight slice
  __shared__ float red[4096];   // 16 KB  cross-wave reduction
  __shared__ float ttr[1024];   //  4 KB  [64 b][16 d] out-transpose staging

  const int bid = blockIdx.x, tid = threadIdx.x;
  const int wave = __builtin_amdgcn_readfirstlane(tid >> 6);  // 0..7, scalar
  const int lane = tid & 63;
  const int bh = bid >> 7, chnk = bid & 127;   // phase-A coords
  const int typ = chnk >> 5;                   // 0:r 1:z 2:h 3:out
  const int b = bh * 64 + lane;
  const int xcls = bid & 7;
  const bool isB = (bid < 128);                // phase-B participants
  const int bh2 = bid >> 6, ch8 = bid & 63;    // phase-B coords
  const int cg = tid >> 6, lane_ = tid & 63;   // epilogue coords

  // ---- initial stage: M1 slice + Uh slice into LDS ----
  {
    const float* src = M1w + (size_t)chnk * 8192;
    #pragma unroll
    for (int i = 0; i < 4; ++i) {
      const int idx4 = tid + i * 512;
      *(float4*)&Ald[idx4 * 4] = *(const float4*)&src[idx4 * 4];
    }
    if (isB) {
      const float* us = Uhw + (size_t)ch8 * 4096;
      *(float4*)&Uld[tid * 4]        = ((const float4*)us)[tid];
      *(float4*)&Uld[2048 + tid * 4] = ((const float4*)us)[512 + tid];
    }
  }
  __syncthreads();

  for (int s = 1; s <= T; ++s) {
    const int p = s & 1;
    const float* hcur = p ? hw1 : hw0;     // s=1 reads hw1 (zeros = h0)
    float* hnxt = p ? hw0 : hw1;
    const uint32_t ph = (uint32_t)(s - 1);

    // ======== phase A : pre = src @ M (+bias), per-type epilogue ========
    {
      const float* hsrc = (s == 1) ? xT : hcur;
      const float* cv = (s == 1) ? c1vec : cvec;
      // typ0 epilogue prefetch: h_prev (keeps the L3 stall off the flag_r path)
      float hpre[2];
      if (typ == 0) {
        #pragma unroll
        for (int i = 0; i < 2; ++i)
          hpre[i] = cload(&hcur[(chnk * 16 + cg * 2 + i) * 128 + bh * 64 + lane_]);
      }
      float acc[16];
      #pragma unroll
      for (int c = 0; c < 16; ++c) acc[c] = 0.f;
      const float* hp = hsrc + (wave * 64) * 128 + b;
      float hv[32];
      #pragma unroll
      for (int u = 0; u < 32; ++u) hv[u] = cload(hp + u * 128);
      #pragma unroll
      for (int u = 0; u < 32; ++u) {              // consume rows 0..31, prefetch 32..63
        const float cur = hv[u];
        hv[u] = cload(hp + (32 + u) * 128);
        const float* mrow = &Ald[(wave * 64 + u) * 16];
        #pragma unroll
        for (int c = 0; c < 16; ++c) acc[c] = fmaf(cur, mrow[c], acc[c]);
      }
      #pragma unroll
      for (int u = 0; u < 32; ++u) {              // peeled tail: rows 32..63
        const float* mrow = &Ald[(wave * 64 + 32 + u) * 16];
        #pragma unroll
        for (int c = 0; c < 16; ++c) acc[c] = fmaf(hv[u], mrow[c], acc[c]);
      }
      // two-stage cross-wave reduction (8 -> 4 -> epilogue)
      if (wave >= 4) {
        #pragma unroll
        for (int c = 0; c < 16; ++c) red[((wave - 4) * 16 + c) * 64 + lane] = acc[c];
      }
      __syncthreads();
      if (wave < 4) {
        #pragma unroll
        for (int c = 0; c < 16; ++c) red[(wave * 16 + c) * 64 + lane] += acc[c];
      }
      __syncthreads();
      const int bb = bh * 64 + lane_;
      float vout[2];
      #pragma unroll
      for (int i = 0; i < 2; ++i) {
        const int c = cg * 2 + i;
        float v = red[c * 64 + lane_] + red[(16 + c) * 64 + lane_]
                + red[(32 + c) * 64 + lane_] + red[(48 + c) * 64 + lane_];
        vout[i] = v + cv[chnk * 16 + c];
      }
      if (typ == 0) {               // r gate -> rh = sigmoid(pre) * h_prev
        #pragma unroll
        for (int i = 0; i < 2; ++i) {
          const int cglob = chnk * 16 + cg * 2 + i;
          cstore(&rhw[cglob * 128 + bb], sigm(vout[i]) * hpre[i]);
        }
        if (s < T) arrive(bar, BAR_R, xcls, 8, ph);
      } else if (typ == 1) {        // z gate (store activated)
        #pragma unroll
        for (int i = 0; i < 2; ++i) {
          const int cglob = chnk * 16 + cg * 2 + i;
          cstore(&Gz[(cglob - 512) * 128 + bb], sigm(vout[i]));
        }
        if (s < T) arrive(bar, BAR_G, xcls, 24, ph);
      } else if (typ == 2) {        // pre-h (x part + bias)
        #pragma unroll
        for (int i = 0; i < 2; ++i) {
          const int cglob = chnk * 16 + cg * 2 + i;
          cstore(&Gh[(cglob - 1024) * 128 + bb], vout[i]);
        }
        if (s < T) arrive(bar, BAR_G, xcls, 24, ph);
      } else {                      // out: arrive FIRST (h reads done), store after
        if (s < T) arrive(bar, BAR_G, xcls, 24, ph);
        if (s > 1) {
          #pragma unroll
          for (int i = 0; i < 2; ++i) ttr[lane_ * 16 + cg * 2 + i] = vout[i];
          __syncthreads();
          const int bq = tid >> 3, pr = tid & 7;
          const float2 o2 = *(const float2*)&ttr[bq * 16 + pr * 2];
          const int bglob = bh * 64 + bq;
          const int d0 = (chnk - 96) * 16 + pr * 2;
          *(float2*)&out[(size_t)bglob * (size_t)T * 512 + (size_t)(s - 1) * 512 + d0] = o2;
        }
      }
    }

    if (s == 1) {
      // restage Ald with the folded M (all A-reads of M1 are done block-locally;
      // next A-read gated by waitf's trailing __syncthreads)
      __syncthreads();
      const float* src = Mw + (size_t)chnk * 8192;
      #pragma unroll
      for (int i = 0; i < 4; ++i) {
        const int idx4 = tid + i * 512;
        *(float4*)&Ald[idx4 * 4] = *(const float4*)&src[idx4 * 4];
      }
      // out[:, 0, :] = inputs (256 blocks x 256 floats)
      if (tid < 256) {
        const int g = bid * 256 + tid;
        out[(size_t)(g >> 9) * (size_t)T * 512 + (g & 511)] = inputs[g];
      }
    }

    if (s < T) {
      // ======== phase B : S = rh @ Uh ; h update (blocks < 128, 8 cols) ========
      if (isB) {
        waitf(bar, BAR_R, xcls, ph);             // rh ready (typ0 done)
        // h_prev prefetch: hcur is stable all step (writes go to hnxt)
        const int cg2 = ch8 * 8 + cg;
        const int bb2 = bh2 * 64 + lane_;
        const float hprev = cload(&hcur[cg2 * 128 + bb2]);
        const float* rp = rhw + (wave * 64) * 128 + bh2 * 64 + lane;
        float hv[32];
        #pragma unroll
        for (int u = 0; u < 32; ++u) hv[u] = cload(rp + u * 128);
        float a2[8];
        #pragma unroll
        for (int c = 0; c < 8; ++c) a2[c] = 0.f;
        #pragma unroll
        for (int u = 0; u < 32; ++u) {
          const float cur = hv[u];
          hv[u] = cload(rp + (32 + u) * 128);
          const float* urow = &Uld[(wave * 64 + u) * 8];
          #pragma unroll
          for (int c = 0; c < 8; ++c) a2[c] = fmaf(cur, urow[c], a2[c]);
        }
        #pragma unroll
        for (int u = 0; u < 32; ++u) {
          const float* urow = &Uld[(wave * 64 + 32 + u) * 8];
          #pragma unroll
          for (int c = 0; c < 8; ++c) a2[c] = fmaf(hv[u], urow[c], a2[c]);
        }
        if (wave >= 4) {
          #pragma unroll
          for (int c = 0; c < 8; ++c) red[((wave - 4) * 8 + c) * 64 + lane] = a2[c];
        }
        __syncthreads();
        if (wave < 4) {
          #pragma unroll
          for (int c = 0; c < 8; ++c) red[(wave * 8 + c) * 64 + lane] += a2[c];
        }
        waitf(bar, BAR_G, xcls, ph);             // Gz/Gh ready (+ doubles as red sync)
        const float zf  = cload(&Gz[cg2 * 128 + bb2]);
        const float ghf = cload(&Gh[cg2 * 128 + bb2]);
        const float S = red[cg * 64 + lane_] + red[(8 + cg) * 64 + lane_]
                      + red[(16 + cg) * 64 + lane_] + red[(24 + cg) * 64 + lane_];
        float hn = (1.f - zf) * hprev + zf * tanh_fast(ghf + S);
        hn = fminf(5.f, fmaxf(-5.f, hn));
        cstore(&hnxt[cg2 * 128 + bb2], hn);
        arrive(bar, BAR_B, xcls, 16, ph);
      }
      waitf(bar, BAR_B, xcls, ph);               // h(s+1) ready -> next step
    }
  }
}

// ======================= host launcher =======================
extern "C" void kernel_launch(void* const* d_in, const int* in_sizes, int n_in,
                              void* d_out, int out_size, void* d_ws, size_t ws_size,
                              hipStream_t stream) {
  const float* inputs = (const float*)d_in[0];
  const float* Wz = (const float*)d_in[1];
  const float* Wr = (const float*)d_in[2];
  const float* Wh = (const float*)d_in[3];
  const float* Uz = (const float*)d_in[4];
  const float* Ur = (const float*)d_in[5];
  const float* Uh = (const float*)d_in[6];
  const float* bz = (const float*)d_in[7];
  const float* br = (const float*)d_in[8];
  const float* bh = (const float*)d_in[9];
  const float* Wo = (const float*)d_in[10];
  const float* bo = (const float*)d_in[11];
  float* ws = (float*)d_ws;
  const int T = out_size / (128 * 512);

  gru_pre<<<dim3(320), dim3(256), 0, stream>>>(inputs, Wz, Wr, Wh, Uz, Ur, Uh,
                                               bz, br, bh, Wo, bo, ws);
  gru_main<<<dim3(256), dim3(512), 0, stream>>>(
      inputs, ws + OFF_M, ws + OFF_M1, ws + OFF_UH, ws + OFF_CV, ws + OFF_C1,
      ws + OFF_H, ws + OFF_H2, ws + OFF_RH, ws + OFF_XT, ws + OFF_GZ, ws + OFF_GH,
      (uint32_t*)(ws + OFF_BAR), (float*)d_out, T);
}